// Round 1
// baseline (461.424 us; speedup 1.0000x reference)
//
#include <hip/hip_runtime.h>
#include <hip/hip_bf16.h>

// Problem dims
#define BB 2
#define QQ 40000
#define CC 128
#define NHH 8
#define NPP 4
#define HH 90
#define WW 160
#define HWW (HH*WW)        // 14400
#define BQ (BB*QQ)         // 80000
#define BHW (BB*HWW)       // 28800

// Generic row-major GEMM: Y[rows,N] = X[rows,128] @ Wm[128,N] + bias
// One block = 256 threads, 16 rows per block, W staged in LDS.
template<int N>
__global__ __launch_bounds__(256) void gemm_k128(
    const float* __restrict__ X, const float* __restrict__ Wm,
    const float* __restrict__ bias, float* __restrict__ Y, int rows)
{
    constexpr int RIF = 256 / N;   // rows in flight per iteration
    constexpr int RPB = 16;        // rows per block
    __shared__ float sW[128 * N];
    __shared__ float sX[RIF][128];
    const int tid = threadIdx.x;
    for (int i = tid; i < 128 * N; i += 256) sW[i] = Wm[i];
    const int col  = tid % N;
    const int rloc = tid / N;
    const float bv = bias[col];
    const long base = (long)blockIdx.x * RPB;
    #pragma unroll
    for (int it = 0; it < RPB / RIF; ++it) {
        __syncthreads();            // covers sW load (it=0) and sX reuse
        const long r0 = base + (long)it * RIF;
        for (int i = tid; i < RIF * 128; i += 256) {
            int rr = i >> 7, cc = i & 127;
            sX[rr][cc] = X[(r0 + rr) * 128 + cc];
        }
        __syncthreads();
        float acc = bv;
        const float4* qx = reinterpret_cast<const float4*>(sX[rloc]);
        #pragma unroll
        for (int k4 = 0; k4 < 32; ++k4) {
            float4 q = qx[k4];
            int kb = k4 * 4;
            acc += q.x * sW[(kb + 0) * N + col];
            acc += q.y * sW[(kb + 1) * N + col];
            acc += q.z * sW[(kb + 2) * N + col];
            acc += q.w * sW[(kb + 3) * N + col];
        }
        Y[(r0 + rloc) * N + col] = acc;
    }
}

// One wave (64 lanes) per query. lane -> (head h = lane>>3, dim-pair dp = lane&7).
// Each lane accumulates 2 of the 16 head dims across 4 points x 4 corners.
__global__ __launch_bounds__(256) void deform_sample(
    const float* __restrict__ v,      // [B,HW,128] projected values
    const float* __restrict__ offs,   // [BQ,64] raw offsets (pixels)
    const float* __restrict__ attnl,  // [BQ,32] raw attn logits
    const float* __restrict__ ref,    // [BQ,2] normalized (x,y)
    float* __restrict__ agg)          // [BQ,128]
{
    const int bq   = blockIdx.x * 4 + (threadIdx.x >> 6);
    const int lane = threadIdx.x & 63;
    const int h  = lane >> 3;
    const int dp = lane & 7;
    const int bsel = (bq >= QQ) ? 1 : 0;

    const float rx = ref[(long)bq * 2 + 0] * (float)WW - 0.5f;
    const float ry = ref[(long)bq * 2 + 1] * (float)HH - 0.5f;

    // softmax over this head's 4 points
    const float* al = attnl + (long)bq * 32 + h * 4;
    float l0 = al[0], l1 = al[1], l2 = al[2], l3 = al[3];
    float m = fmaxf(fmaxf(l0, l1), fmaxf(l2, l3));
    float e0 = __expf(l0 - m), e1 = __expf(l1 - m);
    float e2 = __expf(l2 - m), e3 = __expf(l3 - m);
    float inv = 1.0f / (e0 + e1 + e2 + e3);
    float aw[4] = { e0 * inv, e1 * inv, e2 * inv, e3 * inv };

    const float* ob = offs + (long)bq * 64 + h * 8;
    const float* vb = v + (long)bsel * HWW * 128 + h * 16 + dp * 2;

    float acc0 = 0.0f, acc1 = 0.0f;
    #pragma unroll
    for (int p = 0; p < NPP; ++p) {
        // loc*W - 0.5 == ref*W - 0.5 + off  (offsets are divided by norm then re-multiplied)
        float x = rx + ob[p * 2 + 0];
        float y = ry + ob[p * 2 + 1];
        float x0f = floorf(x), y0f = floorf(y);
        float wx = x - x0f, wy = y - y0f;
        int ix0 = (int)x0f, iy0 = (int)y0f;
        float a = aw[p];
        #pragma unroll
        for (int cy = 0; cy < 2; ++cy) {
            int iy = iy0 + cy;
            float wyc = cy ? wy : (1.0f - wy);
            bool vy = ((unsigned)iy < (unsigned)HH);
            int iyc = min(max(iy, 0), HH - 1);
            #pragma unroll
            for (int cx = 0; cx < 2; ++cx) {
                int ix = ix0 + cx;
                float wxc = cx ? wx : (1.0f - wx);
                bool vx = ((unsigned)ix < (unsigned)WW);
                int ixc = min(max(ix, 0), WW - 1);
                float wgt = (vx && vy) ? (a * wxc * wyc) : 0.0f;
                const float2 g = *reinterpret_cast<const float2*>(vb + ((long)iyc * WW + ixc) * 128);
                acc0 += wgt * g.x;
                acc1 += wgt * g.y;
            }
        }
    }
    float2* out2 = reinterpret_cast<float2*>(agg + (long)bq * 128);
    out2[lane] = make_float2(acc0, acc1);
}

extern "C" void kernel_launch(void* const* d_in, const int* in_sizes, int n_in,
                              void* d_out, int out_size, void* d_ws, size_t ws_size,
                              hipStream_t stream) {
    const float* query = (const float*)d_in[0];
    const float* value = (const float*)d_in[1];
    const float* ref   = (const float*)d_in[2];
    const float* Wv    = (const float*)d_in[3];
    const float* bv    = (const float*)d_in[4];
    const float* Wo    = (const float*)d_in[5];
    const float* bo    = (const float*)d_in[6];
    const float* Wa    = (const float*)d_in[7];
    const float* ba    = (const float*)d_in[8];
    const float* Wout  = (const float*)d_in[9];
    const float* bout  = (const float*)d_in[10];
    float* out = (float*)d_out;

    float* ws    = (float*)d_ws;
    float* v     = ws;                        // 28800*128  = 3,686,400 floats
    float* offs  = v     + (long)BHW * 128;   // 80000*64   = 5,120,000
    float* attnl = offs  + (long)BQ * 64;     // 80000*32   = 2,560,000
    float* agg   = attnl + (long)BQ * 32;     // 80000*128  = 10,240,000
                                              // total ~86.4 MB

    // 1) value projection  v = value @ W_value + b_value
    gemm_k128<128><<<BHW / 16, 256, 0, stream>>>(value, Wv, bv, v, BHW);
    // 2) offset projection (raw pixel offsets)
    gemm_k128<64><<<BQ / 16, 256, 0, stream>>>(query, Wo, bo, offs, BQ);
    // 3) attn logits projection (softmax applied inside sampler)
    gemm_k128<32><<<BQ / 16, 256, 0, stream>>>(query, Wa, ba, attnl, BQ);
    // 4) bilinear sampling + attention-weighted aggregation
    deform_sample<<<BQ / 4, 256, 0, stream>>>(v, offs, attnl, ref, agg);
    // 5) output projection
    gemm_k128<128><<<BQ / 16, 256, 0, stream>>>(agg, Wout, bout, out, BQ);
}

// Round 2
// 185.335 us; speedup vs baseline: 2.4897x; 2.4897x over previous
//
#include <hip/hip_runtime.h>
#include <hip/hip_bf16.h>

// Problem dims
#define BB 2
#define QQ 40000
#define CC 128
#define NHH 8
#define NPP 4
#define HH 90
#define WW 160
#define HWW (HH*WW)        // 14400
#define BQ (BB*QQ)         // 80000
#define BHW (BB*HWW)       // 28800

typedef __attribute__((ext_vector_type(8))) short short8;
typedef __attribute__((ext_vector_type(4))) float f32x4;

static __device__ inline short f2bf(float f) {
    __hip_bfloat16 h = __float2bfloat16(f);
    return __builtin_bit_cast(short, h);
}

// ---------------------------------------------------------------------------
// Prep: convert weights to bf16, transposed [N][K] layout; concat offset+attn.
// ---------------------------------------------------------------------------
__global__ __launch_bounds__(256) void prep_weights(
    const float* __restrict__ Wv, const float* __restrict__ Wo,
    const float* __restrict__ Wa, const float* __restrict__ Wout,
    const float* __restrict__ bo, const float* __restrict__ ba,
    short* __restrict__ wtv, short* __restrict__ wcat,
    short* __restrict__ woutt, float* __restrict__ bcat)
{
    const int t = blockIdx.x * 256 + threadIdx.x;
    const int stride = gridDim.x * 256;
    for (int i = t; i < 128 * 128; i += stride) {
        int n = i >> 7, k = i & 127;
        wtv[i] = f2bf(Wv[k * 128 + n]);
    }
    for (int i = t; i < 96 * 128; i += stride) {
        int n = i >> 7, k = i & 127;
        float w = (n < 64) ? Wo[k * 64 + n] : Wa[k * 32 + (n - 64)];
        wcat[i] = f2bf(w);
    }
    for (int i = t; i < 128 * 128; i += stride) {
        int n = i >> 7, k = i & 127;
        woutt[i] = f2bf(Wout[k * 128 + n]);
    }
    if (t < 96) bcat[t] = (t < 64) ? bo[t] : ba[t - 64];
}

// ---------------------------------------------------------------------------
// MFMA GEMM: Y[rows,N] = X[rows,128] @ W[128,N] + bias
//  - X fp32 row-major, converted to bf16 while staging to LDS (XOR-swizzled)
//  - Wt bf16 [N][128] (pre-transposed), staged to LDS (XOR-swizzled)
//  - block = 256 thr = 4 waves (2x2), block tile 128 x N, wave tile 64 x N/2
//  - mfma_f32_16x16x32_bf16; A-frag lane l: A[l&15][8*(l>>4)+i] (contig 8)
//    B-frag lane l: B[8*(l>>4)+i][l&15]  == Bt[l&15][8*(l>>4)+i]
//  - C/D: col = l&15, row = (l>>4)*4 + reg   [verified layout]
// ---------------------------------------------------------------------------
template<int N, bool OUT_BF16>
__global__ __launch_bounds__(256) void mfma_gemm_k128(
    const float* __restrict__ X, const short* __restrict__ Wt,
    const float* __restrict__ bias, void* __restrict__ Yv)
{
    constexpr int CT = N / 32;                 // col-tiles per wave
    __shared__ short sX[128 * 128];            // bf16 bits, swizzled
    __shared__ short sW[N * 128];              // bf16 bits, swizzled
    const int tid = threadIdx.x;
    const long r0 = (long)blockIdx.x * 128;

    // stage X (fp32 -> bf16), 8B swizzled LDS writes
    for (int i = tid; i < 128 * 32; i += 256) {
        int rr = i >> 5;
        int c4 = (i & 31) * 4;
        float4 xv = reinterpret_cast<const float4*>(X + (r0 + rr) * 128)[i & 31];
        int byo = (rr * 256 + c4 * 2) ^ ((rr & 7) << 4);
        short* p = (short*)((char*)sX + byo);
        p[0] = f2bf(xv.x); p[1] = f2bf(xv.y); p[2] = f2bf(xv.z); p[3] = f2bf(xv.w);
    }
    // stage Wt (bf16), 16B swizzled LDS writes
    for (int i = tid; i < N * 16; i += 256) {
        int nn = i >> 4;
        int c8 = (i & 15) * 8;
        short8 wv = reinterpret_cast<const short8*>(Wt)[i];
        int byo = (nn * 256 + c8 * 2) ^ ((nn & 7) << 4);
        *(short8*)((char*)sW + byo) = wv;
    }
    __syncthreads();

    const int lane = tid & 63, wid = tid >> 6;
    const int wr = wid >> 1, wc = wid & 1;     // 2x2 wave grid
    const int l15 = lane & 15, lg = lane >> 4;

    f32x4 acc[4][CT] = {};
    #pragma unroll
    for (int ks = 0; ks < 4; ++ks) {
        short8 a[4], b[CT];
        #pragma unroll
        for (int rt = 0; rt < 4; ++rt) {
            int row = wr * 64 + rt * 16 + l15;
            int byo = (row * 256 + ks * 64 + lg * 16) ^ ((row & 7) << 4);
            a[rt] = *(const short8*)((const char*)sX + byo);
        }
        #pragma unroll
        for (int ct = 0; ct < CT; ++ct) {
            int n = wc * (N / 2) + ct * 16 + l15;
            int byo = (n * 256 + ks * 64 + lg * 16) ^ ((n & 7) << 4);
            b[ct] = *(const short8*)((const char*)sW + byo);
        }
        #pragma unroll
        for (int rt = 0; rt < 4; ++rt)
            #pragma unroll
            for (int ct = 0; ct < CT; ++ct)
                acc[rt][ct] = __builtin_amdgcn_mfma_f32_16x16x32_bf16(
                    a[rt], b[ct], acc[rt][ct], 0, 0, 0);
    }

    // epilogue: bias + store
    #pragma unroll
    for (int rt = 0; rt < 4; ++rt) {
        #pragma unroll
        for (int ct = 0; ct < CT; ++ct) {
            int col = wc * (N / 2) + ct * 16 + l15;
            float bv = bias[col];
            #pragma unroll
            for (int r = 0; r < 4; ++r) {
                long row = r0 + wr * 64 + rt * 16 + lg * 4 + r;
                float val = acc[rt][ct][r] + bv;
                if (OUT_BF16)
                    ((short*)Yv)[row * N + col] = f2bf(val);
                else
                    ((float*)Yv)[row * N + col] = val;
            }
        }
    }
}

// ---------------------------------------------------------------------------
// Sampler: one wave per query. lane -> (head h = lane>>3, dim-pair dp = lane&7)
// v is bf16 [B,HW,128]; qp fused [BQ,96]: [0,64)=pixel offsets, [64,96)=logits
// ---------------------------------------------------------------------------
__global__ __launch_bounds__(256) void deform_sample(
    const short* __restrict__ v,
    const float* __restrict__ qp,
    const float* __restrict__ ref,
    float* __restrict__ agg)
{
    const int bq   = blockIdx.x * 4 + (threadIdx.x >> 6);
    const int lane = threadIdx.x & 63;
    const int h  = lane >> 3;
    const int dp = lane & 7;
    const int bsel = (bq >= QQ) ? 1 : 0;

    const float rx = ref[(long)bq * 2 + 0] * (float)WW - 0.5f;
    const float ry = ref[(long)bq * 2 + 1] * (float)HH - 0.5f;

    const float* al = qp + (long)bq * 96 + 64 + h * 4;
    float l0 = al[0], l1 = al[1], l2 = al[2], l3 = al[3];
    float m = fmaxf(fmaxf(l0, l1), fmaxf(l2, l3));
    float e0 = __expf(l0 - m), e1 = __expf(l1 - m);
    float e2 = __expf(l2 - m), e3 = __expf(l3 - m);
    float inv = 1.0f / (e0 + e1 + e2 + e3);
    float aw[4] = { e0 * inv, e1 * inv, e2 * inv, e3 * inv };

    const float* ob = qp + (long)bq * 96 + h * 8;
    const short* vb = v + (long)bsel * HWW * 128 + h * 16 + dp * 2;

    float acc0 = 0.0f, acc1 = 0.0f;
    #pragma unroll
    for (int p = 0; p < NPP; ++p) {
        float x = rx + ob[p * 2 + 0];
        float y = ry + ob[p * 2 + 1];
        float x0f = floorf(x), y0f = floorf(y);
        float wx = x - x0f, wy = y - y0f;
        int ix0 = (int)x0f, iy0 = (int)y0f;
        float a = aw[p];
        #pragma unroll
        for (int cy = 0; cy < 2; ++cy) {
            int iy = iy0 + cy;
            float wyc = cy ? wy : (1.0f - wy);
            bool vy = ((unsigned)iy < (unsigned)HH);
            int iyc = min(max(iy, 0), HH - 1);
            #pragma unroll
            for (int cx = 0; cx < 2; ++cx) {
                int ix = ix0 + cx;
                float wxc = cx ? wx : (1.0f - wx);
                bool vx = ((unsigned)ix < (unsigned)WW);
                int ixc = min(max(ix, 0), WW - 1);
                float wgt = (vx && vy) ? (a * wxc * wyc) : 0.0f;
                unsigned u = *reinterpret_cast<const unsigned*>(
                    vb + ((long)iyc * WW + ixc) * 128);
                float g0 = __builtin_bit_cast(float, u << 16);
                float g1 = __builtin_bit_cast(float, u & 0xffff0000u);
                acc0 += wgt * g0;
                acc1 += wgt * g1;
            }
        }
    }
    float2* out2 = reinterpret_cast<float2*>(agg + (long)bq * 128);
    out2[lane] = make_float2(acc0, acc1);
}

extern "C" void kernel_launch(void* const* d_in, const int* in_sizes, int n_in,
                              void* d_out, int out_size, void* d_ws, size_t ws_size,
                              hipStream_t stream) {
    const float* query = (const float*)d_in[0];
    const float* value = (const float*)d_in[1];
    const float* ref   = (const float*)d_in[2];
    const float* Wv    = (const float*)d_in[3];
    const float* bv    = (const float*)d_in[4];
    const float* Wo    = (const float*)d_in[5];
    const float* bo    = (const float*)d_in[6];
    const float* Wa    = (const float*)d_in[7];
    const float* ba    = (const float*)d_in[8];
    const float* Wout  = (const float*)d_in[9];
    const float* bout  = (const float*)d_in[10];
    float* out = (float*)d_out;

    // workspace layout (all 256B-aligned)
    char* ws = (char*)d_ws;
    short* vbf   = (short*)ws;                         // 28800*128 bf16 = 7,372,800 B
    ws += (long)BHW * 128 * 2;
    short* wtv   = (short*)ws;  ws += 128 * 128 * 2;   // 32 KB
    short* wcat  = (short*)ws;  ws += 96 * 128 * 2;    // 24 KB
    short* woutt = (short*)ws;  ws += 128 * 128 * 2;   // 32 KB
    float* bcat  = (float*)ws;  ws += 128 * 4;         // 512 B (96 used)
    float* qp    = (float*)ws;  ws += (long)BQ * 96 * 4;   // 30.72 MB
    float* agg   = (float*)ws;                         // 40.96 MB

    // 0) weight prep (bf16 transposed)
    prep_weights<<<64, 256, 0, stream>>>(Wv, Wo, Wa, Wout, bo, ba,
                                         wtv, wcat, woutt, bcat);
    // 1) value projection -> bf16 v
    mfma_gemm_k128<128, true><<<BHW / 128, 256, 0, stream>>>(value, wtv, bv, vbf);
    // 2) fused offset+attn projection -> fp32 qp [BQ,96]
    mfma_gemm_k128<96, false><<<BQ / 128, 256, 0, stream>>>(query, wcat, bcat, qp);
    // 3) bilinear sampling + attention-weighted aggregation
    deform_sample<<<BQ / 4, 256, 0, stream>>>(vbf, qp, ref, agg);
    // 4) output projection -> d_out
    mfma_gemm_k128<128, false><<<BQ / 128, 256, 0, stream>>>(agg, woutt, bout, out);
}

// Round 3
// 170.488 us; speedup vs baseline: 2.7065x; 1.0871x over previous
//
#include <hip/hip_runtime.h>
#include <hip/hip_bf16.h>

// Problem dims
#define BB 2
#define QQ 40000
#define CC 128
#define NHH 8
#define NPP 4
#define HH 90
#define WW 160
#define HWW (HH*WW)        // 14400
#define BQ (BB*QQ)         // 80000
#define BHW (BB*HWW)       // 28800

typedef __attribute__((ext_vector_type(8))) short short8;
typedef __attribute__((ext_vector_type(4))) float f32x4;

static __device__ inline short f2bf(float f) {
    __hip_bfloat16 h = __float2bfloat16(f);
    return __builtin_bit_cast(short, h);
}

// ---------------------------------------------------------------------------
// Prep: convert weights to bf16, transposed [N][K] layout; concat offset+attn.
// ---------------------------------------------------------------------------
__global__ __launch_bounds__(256) void prep_weights(
    const float* __restrict__ Wv, const float* __restrict__ Wo,
    const float* __restrict__ Wa, const float* __restrict__ Wout,
    const float* __restrict__ bo, const float* __restrict__ ba,
    short* __restrict__ wtv, short* __restrict__ wcat,
    short* __restrict__ woutt, float* __restrict__ bcat)
{
    const int t = blockIdx.x * 256 + threadIdx.x;
    const int stride = gridDim.x * 256;
    for (int i = t; i < 128 * 128; i += stride) {
        int n = i >> 7, k = i & 127;
        wtv[i] = f2bf(Wv[k * 128 + n]);
    }
    for (int i = t; i < 96 * 128; i += stride) {
        int n = i >> 7, k = i & 127;
        float w = (n < 64) ? Wo[k * 64 + n] : Wa[k * 32 + (n - 64)];
        wcat[i] = f2bf(w);
    }
    for (int i = t; i < 128 * 128; i += stride) {
        int n = i >> 7, k = i & 127;
        woutt[i] = f2bf(Wout[k * 128 + n]);
    }
    if (t < 96) bcat[t] = (t < 64) ? bo[t] : ba[t - 64];
}

// ---------------------------------------------------------------------------
// Pipelined MFMA GEMM: Y[rows,N] = X[rows,128] @ W[128,N] + bias
//  - W bf16 [N][128] staged once into LDS (XOR-swizzled), resident for block
//  - tile-strided loop: next tile's X loads issued into regs BEFORE compute,
//    so HBM latency hides under MFMAs (2-phase pipeline, 2 barriers/tile)
//  - XF32: X fp32 (convert to bf16 at ds_write); else X bf16 (short8 path)
//  - block = 256 thr = 4 waves (2x2), block tile 128 x N
//  - mfma_f32_16x16x32_bf16; C/D: col = l&15, row = (l>>4)*4 + reg
// ---------------------------------------------------------------------------
template<int N, bool XF32, bool OUT_BF16>
__global__ __launch_bounds__(256, 2) void gemm_pipe(
    const void* __restrict__ Xv, const short* __restrict__ Wt,
    const float* __restrict__ bias, void* __restrict__ Yv, int ntiles)
{
    constexpr int CT = N / 32;                 // 16-col tiles per wave
    __shared__ short sW[N * 128];
    __shared__ short sX[128 * 128];
    const int tid = threadIdx.x;

    // stage W (swizzled); visibility via first loop barrier
    for (int i = tid; i < N * 16; i += 256) {
        int nn = i >> 4, c8 = (i & 15) * 8;
        short8 wv = reinterpret_cast<const short8*>(Wt)[i];
        *(short8*)((char*)sW + ((nn * 256 + c8 * 2) ^ ((nn & 7) << 4))) = wv;
    }

    const int lane = tid & 63, wid = tid >> 6;
    const int wr = wid >> 1, wc = wid & 1;
    const int l15 = lane & 15, lg = lane >> 4;

    // hoist bias (col is tile-invariant)
    float bvc[CT];
    #pragma unroll
    for (int ct = 0; ct < CT; ++ct) bvc[ct] = bias[wc * (N / 2) + ct * 16 + l15];

    float4 xf[16];
    short8 xb[8];

    int tile = blockIdx.x;
    if (tile < ntiles) {
        if (XF32) {
            const float4* src = reinterpret_cast<const float4*>((const float*)Xv) + (long)tile * 4096;
            #pragma unroll
            for (int j = 0; j < 16; ++j) xf[j] = src[j * 256 + tid];
        } else {
            const short8* src = reinterpret_cast<const short8*>((const short*)Xv) + (long)tile * 2048;
            #pragma unroll
            for (int j = 0; j < 8; ++j) xb[j] = src[j * 256 + tid];
        }
    }

    for (; tile < ntiles; tile += gridDim.x) {
        __syncthreads();   // prior compute done with sX (and sW staged on iter 0)
        if (XF32) {
            #pragma unroll
            for (int j = 0; j < 16; ++j) {
                int flat = j * 256 + tid;          // float4 index
                int row = flat >> 5, c4 = flat & 31;
                int byo = (row * 256 + c4 * 8) ^ ((row & 7) << 4);
                short* p = (short*)((char*)sX + byo);
                p[0] = f2bf(xf[j].x); p[1] = f2bf(xf[j].y);
                p[2] = f2bf(xf[j].z); p[3] = f2bf(xf[j].w);
            }
        } else {
            #pragma unroll
            for (int j = 0; j < 8; ++j) {
                int flat = j * 256 + tid;          // short8 index
                int row = flat >> 4, c8 = flat & 15;
                int byo = (row * 256 + c8 * 16) ^ ((row & 7) << 4);
                *(short8*)((char*)sX + byo) = xb[j];
            }
        }
        // issue next tile's loads now; they fly during compute below (T14)
        int nt = tile + gridDim.x;
        if (nt < ntiles) {
            if (XF32) {
                const float4* src = reinterpret_cast<const float4*>((const float*)Xv) + (long)nt * 4096;
                #pragma unroll
                for (int j = 0; j < 16; ++j) xf[j] = src[j * 256 + tid];
            } else {
                const short8* src = reinterpret_cast<const short8*>((const short*)Xv) + (long)nt * 2048;
                #pragma unroll
                for (int j = 0; j < 8; ++j) xb[j] = src[j * 256 + tid];
            }
        }
        __syncthreads();

        f32x4 acc[4][CT] = {};
        #pragma unroll
        for (int ks = 0; ks < 4; ++ks) {
            short8 a[4], b[CT];
            #pragma unroll
            for (int rt = 0; rt < 4; ++rt) {
                int row = wr * 64 + rt * 16 + l15;
                a[rt] = *(const short8*)((const char*)sX +
                        ((row * 256 + ks * 64 + lg * 16) ^ ((row & 7) << 4)));
            }
            #pragma unroll
            for (int ct = 0; ct < CT; ++ct) {
                int n = wc * (N / 2) + ct * 16 + l15;
                b[ct] = *(const short8*)((const char*)sW +
                        ((n * 256 + ks * 64 + lg * 16) ^ ((n & 7) << 4)));
            }
            #pragma unroll
            for (int rt = 0; rt < 4; ++rt)
                #pragma unroll
                for (int ct = 0; ct < CT; ++ct)
                    acc[rt][ct] = __builtin_amdgcn_mfma_f32_16x16x32_bf16(
                        a[rt], b[ct], acc[rt][ct], 0, 0, 0);
        }

        const long r0 = (long)tile * 128;
        #pragma unroll
        for (int rt = 0; rt < 4; ++rt) {
            #pragma unroll
            for (int ct = 0; ct < CT; ++ct) {
                int col = wc * (N / 2) + ct * 16 + l15;
                #pragma unroll
                for (int r = 0; r < 4; ++r) {
                    long row = r0 + wr * 64 + rt * 16 + lg * 4 + r;
                    float val = acc[rt][ct][r] + bvc[ct];
                    if (OUT_BF16) ((short*)Yv)[row * N + col] = f2bf(val);
                    else          ((float*)Yv)[row * N + col] = val;
                }
            }
        }
    }
}

// ---------------------------------------------------------------------------
// Sampler: one wave per query. lane -> (head h = lane>>3, dim-pair dp = lane&7)
// v bf16 [B,HW,128]; qp fp32 [BQ,96]: [0,64)=pixel offsets, [64,96)=logits
// agg written as packed bf16 (identical rounding to the old GEMM-staging cvt)
// ---------------------------------------------------------------------------
__global__ __launch_bounds__(256) void deform_sample(
    const short* __restrict__ v,
    const float* __restrict__ qp,
    const float* __restrict__ ref,
    unsigned* __restrict__ agg)   // [BQ,64] packed 2xbf16
{
    const int bq   = blockIdx.x * 4 + (threadIdx.x >> 6);
    const int lane = threadIdx.x & 63;
    const int h  = lane >> 3;
    const int dp = lane & 7;
    const int bsel = (bq >= QQ) ? 1 : 0;

    const float rx = ref[(long)bq * 2 + 0] * (float)WW - 0.5f;
    const float ry = ref[(long)bq * 2 + 1] * (float)HH - 0.5f;

    const float* al = qp + (long)bq * 96 + 64 + h * 4;
    float l0 = al[0], l1 = al[1], l2 = al[2], l3 = al[3];
    float m = fmaxf(fmaxf(l0, l1), fmaxf(l2, l3));
    float e0 = __expf(l0 - m), e1 = __expf(l1 - m);
    float e2 = __expf(l2 - m), e3 = __expf(l3 - m);
    float inv = 1.0f / (e0 + e1 + e2 + e3);
    float aw[4] = { e0 * inv, e1 * inv, e2 * inv, e3 * inv };

    const float* ob = qp + (long)bq * 96 + h * 8;
    const short* vb = v + (long)bsel * HWW * 128 + h * 16 + dp * 2;

    float acc0 = 0.0f, acc1 = 0.0f;
    #pragma unroll
    for (int p = 0; p < NPP; ++p) {
        float x = rx + ob[p * 2 + 0];
        float y = ry + ob[p * 2 + 1];
        float x0f = floorf(x), y0f = floorf(y);
        float wx = x - x0f, wy = y - y0f;
        int ix0 = (int)x0f, iy0 = (int)y0f;
        float a = aw[p];
        #pragma unroll
        for (int cy = 0; cy < 2; ++cy) {
            int iy = iy0 + cy;
            float wyc = cy ? wy : (1.0f - wy);
            bool vy = ((unsigned)iy < (unsigned)HH);
            int iyc = min(max(iy, 0), HH - 1);
            #pragma unroll
            for (int cx = 0; cx < 2; ++cx) {
                int ix = ix0 + cx;
                float wxc = cx ? wx : (1.0f - wx);
                bool vx = ((unsigned)ix < (unsigned)WW);
                int ixc = min(max(ix, 0), WW - 1);
                float wgt = (vx && vy) ? (a * wxc * wyc) : 0.0f;
                unsigned u = *reinterpret_cast<const unsigned*>(
                    vb + ((long)iyc * WW + ixc) * 128);
                float g0 = __builtin_bit_cast(float, u << 16);
                float g1 = __builtin_bit_cast(float, u & 0xffff0000u);
                acc0 += wgt * g0;
                acc1 += wgt * g1;
            }
        }
    }
    unsigned pk = (unsigned)(unsigned short)f2bf(acc0)
                | ((unsigned)(unsigned short)f2bf(acc1) << 16);
    agg[(long)bq * 64 + lane] = pk;
}

extern "C" void kernel_launch(void* const* d_in, const int* in_sizes, int n_in,
                              void* d_out, int out_size, void* d_ws, size_t ws_size,
                              hipStream_t stream) {
    const float* query = (const float*)d_in[0];
    const float* value = (const float*)d_in[1];
    const float* ref   = (const float*)d_in[2];
    const float* Wv    = (const float*)d_in[3];
    const float* bv    = (const float*)d_in[4];
    const float* Wo    = (const float*)d_in[5];
    const float* bo    = (const float*)d_in[6];
    const float* Wa    = (const float*)d_in[7];
    const float* ba    = (const float*)d_in[8];
    const float* Wout  = (const float*)d_in[9];
    const float* bout  = (const float*)d_in[10];
    float* out = (float*)d_out;

    // workspace layout (256B-aligned chunks)
    char* ws = (char*)d_ws;
    short* vbf   = (short*)ws;  ws += (long)BHW * 128 * 2;   // 7.37 MB
    short* wtv   = (short*)ws;  ws += 128 * 128 * 2;         // 32 KB
    short* wcat  = (short*)ws;  ws += 96 * 128 * 2;          // 24 KB
    short* woutt = (short*)ws;  ws += 128 * 128 * 2;         // 32 KB
    float* bcat  = (float*)ws;  ws += 128 * 4;               // 512 B
    float* qp    = (float*)ws;  ws += (long)BQ * 96 * 4;     // 30.72 MB
    unsigned* aggb = (unsigned*)ws;                          // 20.48 MB

    const int ntV = BHW / 128;   // 225
    const int ntQ = BQ / 128;    // 625
    const int gV = ntV < 512 ? ntV : 512;
    const int gQ = ntQ < 512 ? ntQ : 512;

    // 0) weight prep (bf16 transposed)
    prep_weights<<<64, 256, 0, stream>>>(Wv, Wo, Wa, Wout, bo, ba,
                                         wtv, wcat, woutt, bcat);
    // 1) value projection -> bf16 v
    gemm_pipe<128, true, true><<<gV, 256, 0, stream>>>(value, wtv, bv, vbf, ntV);
    // 2) fused offset+attn projection -> fp32 qp [BQ,96]
    gemm_pipe<96, true, false><<<gQ, 256, 0, stream>>>(query, wcat, bcat, qp, ntQ);
    // 3) bilinear sampling + attention-weighted aggregation -> bf16 agg
    deform_sample<<<BQ / 4, 256, 0, stream>>>(vbf, qp, ref, aggb);
    // 4) output projection -> d_out
    gemm_pipe<128, false, false><<<gQ, 256, 0, stream>>>(aggb, woutt, bout, out, ntQ);
}

// Round 5
// 164.089 us; speedup vs baseline: 2.8120x; 1.0390x over previous
//
#include <hip/hip_runtime.h>
#include <hip/hip_bf16.h>

// Problem dims
#define BB 2
#define QQ 40000
#define CC 128
#define NHH 8
#define NPP 4
#define HH 90
#define WW 160
#define HWW (HH*WW)        // 14400
#define BQ (BB*QQ)         // 80000
#define BHW (BB*HWW)       // 28800

typedef __attribute__((ext_vector_type(8))) short short8;
typedef __attribute__((ext_vector_type(4))) unsigned short ushortx4;
typedef __attribute__((ext_vector_type(4))) float f32x4;

static __device__ inline short f2bf(float f) {
    __hip_bfloat16 h = __float2bfloat16(f);
    return __builtin_bit_cast(short, h);
}
static __device__ inline float bfu(unsigned short u) {
    return __builtin_bit_cast(float, ((unsigned)u) << 16);
}

// ---------------------------------------------------------------------------
// Prep: convert weights to bf16, transposed [N][K] layout; concat offset+attn.
// ---------------------------------------------------------------------------
__global__ __launch_bounds__(256) void prep_weights(
    const float* __restrict__ Wv, const float* __restrict__ Wo,
    const float* __restrict__ Wa, const float* __restrict__ Wout,
    const float* __restrict__ bo, const float* __restrict__ ba,
    short* __restrict__ wtv, short* __restrict__ wcat,
    short* __restrict__ woutt, float* __restrict__ bcat)
{
    const int t = blockIdx.x * 256 + threadIdx.x;
    const int stride = gridDim.x * 256;
    for (int i = t; i < 128 * 128; i += stride) {
        int n = i >> 7, k = i & 127;
        wtv[i] = f2bf(Wv[k * 128 + n]);
    }
    for (int i = t; i < 96 * 128; i += stride) {
        int n = i >> 7, k = i & 127;
        float w = (n < 64) ? Wo[k * 64 + n] : Wa[k * 32 + (n - 64)];
        wcat[i] = f2bf(w);
    }
    for (int i = t; i < 128 * 128; i += stride) {
        int n = i >> 7, k = i & 127;
        woutt[i] = f2bf(Wout[k * 128 + n]);
    }
    if (t < 96) bcat[t] = (t < 64) ? bo[t] : ba[t - 64];
}

// ---------------------------------------------------------------------------
// Pipelined MFMA GEMM: Y[rows,N] = X[rows,128] @ W[128,N] + bias
// (unchanged structure from round 3; used for value-proj and qp-proj)
// ---------------------------------------------------------------------------
template<int N, bool XF32, bool OUT_BF16>
__global__ __launch_bounds__(256, 2) void gemm_pipe(
    const void* __restrict__ Xv, const short* __restrict__ Wt,
    const float* __restrict__ bias, void* __restrict__ Yv, int ntiles)
{
    constexpr int CT = N / 32;
    __shared__ short sW[N * 128];
    __shared__ short sX[128 * 128];
    const int tid = threadIdx.x;

    for (int i = tid; i < N * 16; i += 256) {
        int nn = i >> 4, c8 = (i & 15) * 8;
        short8 wv = reinterpret_cast<const short8*>(Wt)[i];
        *(short8*)((char*)sW + ((nn * 256 + c8 * 2) ^ ((nn & 7) << 4))) = wv;
    }

    const int lane = tid & 63, wid = tid >> 6;
    const int wr = wid >> 1, wc = wid & 1;
    const int l15 = lane & 15, lg = lane >> 4;

    float bvc[CT];
    #pragma unroll
    for (int ct = 0; ct < CT; ++ct) bvc[ct] = bias[wc * (N / 2) + ct * 16 + l15];

    float4 xf[16];
    short8 xb[8];

    int tile = blockIdx.x;
    if (tile < ntiles) {
        if (XF32) {
            const float4* src = reinterpret_cast<const float4*>((const float*)Xv) + (long)tile * 4096;
            #pragma unroll
            for (int j = 0; j < 16; ++j) xf[j] = src[j * 256 + tid];
        } else {
            const short8* src = reinterpret_cast<const short8*>((const short*)Xv) + (long)tile * 2048;
            #pragma unroll
            for (int j = 0; j < 8; ++j) xb[j] = src[j * 256 + tid];
        }
    }

    for (; tile < ntiles; tile += gridDim.x) {
        __syncthreads();
        if (XF32) {
            #pragma unroll
            for (int j = 0; j < 16; ++j) {
                int flat = j * 256 + tid;
                int row = flat >> 5, c4 = flat & 31;
                int byo = (row * 256 + c4 * 8) ^ ((row & 7) << 4);
                short* p = (short*)((char*)sX + byo);
                p[0] = f2bf(xf[j].x); p[1] = f2bf(xf[j].y);
                p[2] = f2bf(xf[j].z); p[3] = f2bf(xf[j].w);
            }
        } else {
            #pragma unroll
            for (int j = 0; j < 8; ++j) {
                int flat = j * 256 + tid;
                int row = flat >> 4, c8 = flat & 15;
                int byo = (row * 256 + c8 * 16) ^ ((row & 7) << 4);
                *(short8*)((char*)sX + byo) = xb[j];
            }
        }
        int nt = tile + gridDim.x;
        if (nt < ntiles) {
            if (XF32) {
                const float4* src = reinterpret_cast<const float4*>((const float*)Xv) + (long)nt * 4096;
                #pragma unroll
                for (int j = 0; j < 16; ++j) xf[j] = src[j * 256 + tid];
            } else {
                const short8* src = reinterpret_cast<const short8*>((const short*)Xv) + (long)nt * 2048;
                #pragma unroll
                for (int j = 0; j < 8; ++j) xb[j] = src[j * 256 + tid];
            }
        }
        __syncthreads();

        f32x4 acc[4][CT] = {};
        #pragma unroll
        for (int ks = 0; ks < 4; ++ks) {
            short8 a[4], b[CT];
            #pragma unroll
            for (int rt = 0; rt < 4; ++rt) {
                int row = wr * 64 + rt * 16 + l15;
                a[rt] = *(const short8*)((const char*)sX +
                        ((row * 256 + ks * 64 + lg * 16) ^ ((row & 7) << 4)));
            }
            #pragma unroll
            for (int ct = 0; ct < CT; ++ct) {
                int n = wc * (N / 2) + ct * 16 + l15;
                b[ct] = *(const short8*)((const char*)sW +
                        ((n * 256 + ks * 64 + lg * 16) ^ ((n & 7) << 4)));
            }
            #pragma unroll
            for (int rt = 0; rt < 4; ++rt)
                #pragma unroll
                for (int ct = 0; ct < CT; ++ct)
                    acc[rt][ct] = __builtin_amdgcn_mfma_f32_16x16x32_bf16(
                        a[rt], b[ct], acc[rt][ct], 0, 0, 0);
        }

        const long r0 = (long)tile * 128;
        #pragma unroll
        for (int rt = 0; rt < 4; ++rt) {
            #pragma unroll
            for (int ct = 0; ct < CT; ++ct) {
                int col = wc * (N / 2) + ct * 16 + l15;
                #pragma unroll
                for (int r = 0; r < 4; ++r) {
                    long row = r0 + wr * 64 + rt * 16 + lg * 4 + r;
                    float val = acc[rt][ct][r] + bvc[ct];
                    if (OUT_BF16) ((short*)Yv)[row * N + col] = f2bf(val);
                    else          ((float*)Yv)[row * N + col] = val;
                }
            }
        }
    }
}

// ---------------------------------------------------------------------------
// Fused sampler + output projection. One block = 128 queries (one tile).
// Sampling: 16 lanes/query (lane -> 8 dims of one head), 4 queries/wave,
// 8 passes/wave -> 32 queries/wave. agg tile -> LDS bf16 (swizzled).
// Then 128x128x128 MFMA with resident Wout, + bias, store fp32 out.
// ---------------------------------------------------------------------------
__global__ __launch_bounds__(256, 2) void sample_out(
    const short* __restrict__ v,      // bf16 [B,HW,128]
    const short* __restrict__ qp,     // bf16 [BQ,96]: [0,64) offsets px, [64,96) logits
    const float* __restrict__ ref,    // fp32 [BQ,2]
    const short* __restrict__ Wt,     // bf16 [128][128] W_out^T
    const float* __restrict__ bias,   // fp32 [128]
    float* __restrict__ out)          // fp32 [BQ,128]
{
    __shared__ short sAgg[128 * 128]; // 32 KB, swizzled
    __shared__ short sW[128 * 128];   // 32 KB, swizzled
    const int tid = threadIdx.x;
    const int lane = tid & 63, wid = tid >> 6;
    const long tile0 = (long)blockIdx.x * 128;

    // stage Wout tile (visibility covered by the post-sampling barrier)
    for (int i = tid; i < 128 * 16; i += 256) {
        int nn = i >> 4, c8 = (i & 15) * 8;
        short8 wv = reinterpret_cast<const short8*>(Wt)[i];
        *(short8*)((char*)sW + ((nn * 256 + c8 * 2) ^ ((nn & 7) << 4))) = wv;
    }

    const int q4 = lane >> 4;       // query slot within wave (0..3)
    const int l  = lane & 15;       // dim-chunk: dims [l*8, l*8+8), head = l>>1
    const int h  = l >> 1;

    #pragma unroll
    for (int pass = 0; pass < 8; ++pass) {
        const int lq = wid * 32 + pass * 4 + q4;
        const long bq = tile0 + lq;
        const int bsel = (bq >= QQ) ? 1 : 0;

        const float rx = ref[bq * 2 + 0] * (float)WW - 0.5f;
        const float ry = ref[bq * 2 + 1] * (float)HH - 0.5f;

        const short* qpb = qp + bq * 96;
        // softmax over this head's 4 logits (bf16)
        ushortx4 lg4 = *reinterpret_cast<const ushortx4*>(qpb + 64 + h * 4);
        float l0 = bfu(lg4[0]), l1 = bfu(lg4[1]), l2 = bfu(lg4[2]), l3 = bfu(lg4[3]);
        float m = fmaxf(fmaxf(l0, l1), fmaxf(l2, l3));
        float e0 = __expf(l0 - m), e1 = __expf(l1 - m);
        float e2 = __expf(l2 - m), e3 = __expf(l3 - m);
        float inv = 1.0f / (e0 + e1 + e2 + e3);
        float aw[4] = { e0 * inv, e1 * inv, e2 * inv, e3 * inv };

        // this head's 8 pixel offsets (bf16)
        short8 ob = *reinterpret_cast<const short8*>(qpb + h * 8);
        float ofs[8];
        #pragma unroll
        for (int j = 0; j < 8; ++j) ofs[j] = bfu((unsigned short)ob[j]);

        const short* vb = v + (long)bsel * HWW * 128 + l * 8;

        float ac[8] = {0,0,0,0,0,0,0,0};
        #pragma unroll
        for (int p = 0; p < NPP; ++p) {
            float x = rx + ofs[p * 2 + 0];
            float y = ry + ofs[p * 2 + 1];
            float x0f = floorf(x), y0f = floorf(y);
            float wx = x - x0f, wy = y - y0f;
            int ix0 = (int)x0f, iy0 = (int)y0f;
            float wxs[2] = { 1.0f - wx, wx };
            float wys[2] = { 1.0f - wy, wy };
            #pragma unroll
            for (int cy = 0; cy < 2; ++cy) {
                int iy = iy0 + cy;
                bool vy = ((unsigned)iy < (unsigned)HH);
                int iyc = min(max(iy, 0), HH - 1);
                #pragma unroll
                for (int cx = 0; cx < 2; ++cx) {
                    int ix = ix0 + cx;
                    bool vx = ((unsigned)ix < (unsigned)WW);
                    int ixc = min(max(ix, 0), WW - 1);
                    float wgt = (vx && vy) ? (aw[p] * wxs[cx] * wys[cy]) : 0.0f;
                    short8 g = *reinterpret_cast<const short8*>(vb + (iyc * WW + ixc) * 128);
                    #pragma unroll
                    for (int j = 0; j < 8; ++j)
                        ac[j] += wgt * bfu((unsigned short)g[j]);
                }
            }
        }
        // pack and write agg row to LDS (swizzled)
        short8 pk;
        #pragma unroll
        for (int j = 0; j < 8; ++j) pk[j] = f2bf(ac[j]);
        *(short8*)((char*)sAgg + ((lq * 256 + l * 16) ^ ((lq & 7) << 4))) = pk;
    }
    __syncthreads();

    // out-projection MFMA: out_tile = agg_tile @ Wout + bias
    const int wr = wid >> 1, wc = wid & 1;
    const int l15 = lane & 15, lg = lane >> 4;
    f32x4 acc[4][4] = {};
    #pragma unroll
    for (int ks = 0; ks < 4; ++ks) {
        short8 a[4], b[4];
        #pragma unroll
        for (int rt = 0; rt < 4; ++rt) {
            int row = wr * 64 + rt * 16 + l15;
            a[rt] = *(const short8*)((const char*)sAgg +
                    ((row * 256 + ks * 64 + lg * 16) ^ ((row & 7) << 4)));
        }
        #pragma unroll
        for (int ct = 0; ct < 4; ++ct) {
            int n = wc * 64 + ct * 16 + l15;
            b[ct] = *(const short8*)((const char*)sW +
                    ((n * 256 + ks * 64 + lg * 16) ^ ((n & 7) << 4)));
        }
        #pragma unroll
        for (int rt = 0; rt < 4; ++rt)
            #pragma unroll
            for (int ct = 0; ct < 4; ++ct)
                acc[rt][ct] = __builtin_amdgcn_mfma_f32_16x16x32_bf16(
                    a[rt], b[ct], acc[rt][ct], 0, 0, 0);
    }
    #pragma unroll
    for (int rt = 0; rt < 4; ++rt) {
        #pragma unroll
        for (int ct = 0; ct < 4; ++ct) {
            int col = wc * 64 + ct * 16 + l15;
            float bv = bias[col];
            #pragma unroll
            for (int r = 0; r < 4; ++r) {
                long row = tile0 + wr * 64 + rt * 16 + lg * 4 + r;
                out[row * 128 + col] = acc[rt][ct][r] + bv;
            }
        }
    }
}

extern "C" void kernel_launch(void* const* d_in, const int* in_sizes, int n_in,
                              void* d_out, int out_size, void* d_ws, size_t ws_size,
                              hipStream_t stream) {
    const float* query = (const float*)d_in[0];
    const float* value = (const float*)d_in[1];
    const float* ref   = (const float*)d_in[2];
    const float* Wv    = (const float*)d_in[3];
    const float* bv    = (const float*)d_in[4];
    const float* Wo    = (const float*)d_in[5];
    const float* bo    = (const float*)d_in[6];
    const float* Wa    = (const float*)d_in[7];
    const float* ba    = (const float*)d_in[8];
    const float* Wout  = (const float*)d_in[9];
    const float* bout  = (const float*)d_in[10];
    float* out = (float*)d_out;

    // workspace layout (256B-aligned chunks)
    char* ws = (char*)d_ws;
    short* vbf   = (short*)ws;  ws += (long)BHW * 128 * 2;   // 7.37 MB
    short* wtv   = (short*)ws;  ws += 128 * 128 * 2;         // 32 KB
    short* wcat  = (short*)ws;  ws += 96 * 128 * 2;          // 24 KB
    short* woutt = (short*)ws;  ws += 128 * 128 * 2;         // 32 KB
    float* bcat  = (float*)ws;  ws += 128 * 4;               // 512 B
    short* qpb   = (short*)ws;                               // 15.36 MB (bf16 [BQ,96])

    const int ntV = BHW / 128;   // 225
    const int ntQ = BQ / 128;    // 625
    const int gV = ntV < 512 ? ntV : 512;
    const int gQ = ntQ < 512 ? ntQ : 512;

    // 0) weight prep (bf16 transposed)
    prep_weights<<<64, 256, 0, stream>>>(Wv, Wo, Wa, Wout, bo, ba,
                                         wtv, wcat, woutt, bcat);
    // 1) value projection -> bf16 v
    gemm_pipe<128, true, true><<<gV, 256, 0, stream>>>(value, wtv, bv, vbf, ntV);
    // 2) fused offset+attn projection -> bf16 qp [BQ,96]
    gemm_pipe<96, true, true><<<gQ, 256, 0, stream>>>(query, wcat, bcat, qpb, ntQ);
    // 3) fused bilinear sampling + aggregation + output projection -> d_out
    sample_out<<<ntQ, 256, 0, stream>>>(vbf, qpb, ref, woutt, bout, out);
}

// Round 8
// 161.639 us; speedup vs baseline: 2.8547x; 1.0152x over previous
//
#include <hip/hip_runtime.h>
#include <hip/hip_bf16.h>

// Problem dims
#define BB 2
#define QQ 40000
#define CC 128
#define NHH 8
#define NPP 4
#define HH 90
#define WW 160
#define HWW (HH*WW)        // 14400
#define BQ (BB*QQ)         // 80000
#define BHW (BB*HWW)       // 28800

typedef __attribute__((ext_vector_type(8))) short short8;
typedef __attribute__((ext_vector_type(4))) unsigned short ushortx4;
typedef __attribute__((ext_vector_type(4))) float f32x4;

static __device__ inline short f2bf(float f) {
    __hip_bfloat16 h = __float2bfloat16(f);
    return __builtin_bit_cast(short, h);
}
static __device__ inline float bfu(unsigned short u) {
    return __builtin_bit_cast(float, ((unsigned)u) << 16);
}

// ---------------------------------------------------------------------------
// Prep: convert weights to bf16, transposed [N][K] layout; concat offset+attn.
// ---------------------------------------------------------------------------
__global__ __launch_bounds__(256) void prep_weights(
    const float* __restrict__ Wv, const float* __restrict__ Wo,
    const float* __restrict__ Wa, const float* __restrict__ Wout,
    const float* __restrict__ bo, const float* __restrict__ ba,
    short* __restrict__ wtv, short* __restrict__ wcat,
    short* __restrict__ woutt, float* __restrict__ bcat)
{
    const int t = blockIdx.x * 256 + threadIdx.x;
    const int stride = gridDim.x * 256;
    for (int i = t; i < 128 * 128; i += stride) {
        int n = i >> 7, k = i & 127;
        wtv[i] = f2bf(Wv[k * 128 + n]);
    }
    for (int i = t; i < 96 * 128; i += stride) {
        int n = i >> 7, k = i & 127;
        float w = (n < 64) ? Wo[k * 64 + n] : Wa[k * 32 + (n - 64)];
        wcat[i] = f2bf(w);
    }
    for (int i = t; i < 128 * 128; i += stride) {
        int n = i >> 7, k = i & 127;
        woutt[i] = f2bf(Wout[k * 128 + n]);
    }
    if (t < 96) bcat[t] = (t < 64) ? bo[t] : ba[t - 64];
}

// ---------------------------------------------------------------------------
// Pipelined MFMA GEMM: Y[rows,N] = X[rows,128] @ W[128,N] + bias
// (same structure as round 3; used for value-proj, qp-proj, out-proj)
// ---------------------------------------------------------------------------
template<int N, bool XF32, bool OUT_BF16>
__global__ __launch_bounds__(256, 2) void gemm_pipe(
    const void* __restrict__ Xv, const short* __restrict__ Wt,
    const float* __restrict__ bias, void* __restrict__ Yv, int ntiles)
{
    constexpr int CT = N / 32;
    __shared__ short sW[N * 128];
    __shared__ short sX[128 * 128];
    const int tid = threadIdx.x;

    for (int i = tid; i < N * 16; i += 256) {
        int nn = i >> 4, c8 = (i & 15) * 8;
        short8 wv = reinterpret_cast<const short8*>(Wt)[i];
        *(short8*)((char*)sW + ((nn * 256 + c8 * 2) ^ ((nn & 7) << 4))) = wv;
    }

    const int lane = tid & 63, wid = tid >> 6;
    const int wr = wid >> 1, wc = wid & 1;
    const int l15 = lane & 15, lg = lane >> 4;

    float bvc[CT];
    #pragma unroll
    for (int ct = 0; ct < CT; ++ct) bvc[ct] = bias[wc * (N / 2) + ct * 16 + l15];

    float4 xf[16];
    short8 xb[8];

    int tile = blockIdx.x;
    if (tile < ntiles) {
        if (XF32) {
            const float4* src = reinterpret_cast<const float4*>((const float*)Xv) + (long)tile * 4096;
            #pragma unroll
            for (int j = 0; j < 16; ++j) xf[j] = src[j * 256 + tid];
        } else {
            const short8* src = reinterpret_cast<const short8*>((const short*)Xv) + (long)tile * 2048;
            #pragma unroll
            for (int j = 0; j < 8; ++j) xb[j] = src[j * 256 + tid];
        }
    }

    for (; tile < ntiles; tile += gridDim.x) {
        __syncthreads();
        if (XF32) {
            #pragma unroll
            for (int j = 0; j < 16; ++j) {
                int flat = j * 256 + tid;
                int row = flat >> 5, c4 = flat & 31;
                int byo = (row * 256 + c4 * 8) ^ ((row & 7) << 4);
                short* p = (short*)((char*)sX + byo);
                p[0] = f2bf(xf[j].x); p[1] = f2bf(xf[j].y);
                p[2] = f2bf(xf[j].z); p[3] = f2bf(xf[j].w);
            }
        } else {
            #pragma unroll
            for (int j = 0; j < 8; ++j) {
                int flat = j * 256 + tid;
                int row = flat >> 4, c8 = flat & 15;
                int byo = (row * 256 + c8 * 16) ^ ((row & 7) << 4);
                *(short8*)((char*)sX + byo) = xb[j];
            }
        }
        int nt = tile + gridDim.x;
        if (nt < ntiles) {
            if (XF32) {
                const float4* src = reinterpret_cast<const float4*>((const float*)Xv) + (long)nt * 4096;
                #pragma unroll
                for (int j = 0; j < 16; ++j) xf[j] = src[j * 256 + tid];
            } else {
                const short8* src = reinterpret_cast<const short8*>((const short*)Xv) + (long)nt * 2048;
                #pragma unroll
                for (int j = 0; j < 8; ++j) xb[j] = src[j * 256 + tid];
            }
        }
        __syncthreads();

        f32x4 acc[4][CT] = {};
        #pragma unroll
        for (int ks = 0; ks < 4; ++ks) {
            short8 a[4], b[CT];
            #pragma unroll
            for (int rt = 0; rt < 4; ++rt) {
                int row = wr * 64 + rt * 16 + l15;
                a[rt] = *(const short8*)((const char*)sX +
                        ((row * 256 + ks * 64 + lg * 16) ^ ((row & 7) << 4)));
            }
            #pragma unroll
            for (int ct = 0; ct < CT; ++ct) {
                int n = wc * (N / 2) + ct * 16 + l15;
                b[ct] = *(const short8*)((const char*)sW +
                        ((n * 256 + ks * 64 + lg * 16) ^ ((n & 7) << 4)));
            }
            #pragma unroll
            for (int rt = 0; rt < 4; ++rt)
                #pragma unroll
                for (int ct = 0; ct < CT; ++ct)
                    acc[rt][ct] = __builtin_amdgcn_mfma_f32_16x16x32_bf16(
                        a[rt], b[ct], acc[rt][ct], 0, 0, 0);
        }

        const long r0 = (long)tile * 128;
        #pragma unroll
        for (int rt = 0; rt < 4; ++rt) {
            #pragma unroll
            for (int ct = 0; ct < CT; ++ct) {
                int col = wc * (N / 2) + ct * 16 + l15;
                #pragma unroll
                for (int r = 0; r < 4; ++r) {
                    long row = r0 + wr * 64 + rt * 16 + lg * 4 + r;
                    float val = acc[rt][ct][r] + bvc[ct];
                    if (OUT_BF16) ((short*)Yv)[row * N + col] = f2bf(val);
                    else          ((float*)Yv)[row * N + col] = val;
                }
            }
        }
    }
}

// ---------------------------------------------------------------------------
// Standalone sampler, 16 lanes per query, no LDS (occupancy-first).
// thread t -> query q = t>>4, dim-chunk l = t&15 (dims [l*8, l*8+8), head l>>1).
// Gathers are 16B/lane, 256B contiguous per (query, corner) -> fully coalesced.
// Writes agg as bf16 [BQ,128] (short8 per lane, 1KB contiguous per wave).
// ---------------------------------------------------------------------------
__global__ __launch_bounds__(256) void deform_sample16(
    const short* __restrict__ v,      // bf16 [B,HW,128]
    const short* __restrict__ qp,     // bf16 [BQ,96]: [0,64) offsets px, [64,96) logits
    const float* __restrict__ ref,    // fp32 [BQ,2]
    short* __restrict__ agg)          // bf16 [BQ,128]
{
    const int t = blockIdx.x * 256 + threadIdx.x;
    const long q = t >> 4;            // query index
    const int l = t & 15;             // dim chunk
    const int h = l >> 1;             // head
    const int bsel = (q >= QQ) ? 1 : 0;

    const float rx = ref[q * 2 + 0] * (float)WW - 0.5f;
    const float ry = ref[q * 2 + 1] * (float)HH - 0.5f;

    const short* qpb = qp + q * 96;
    // softmax over this head's 4 logits (bf16)
    ushortx4 lg4 = *reinterpret_cast<const ushortx4*>(qpb + 64 + h * 4);
    float l0 = bfu(lg4[0]), l1 = bfu(lg4[1]), l2 = bfu(lg4[2]), l3 = bfu(lg4[3]);
    float m = fmaxf(fmaxf(l0, l1), fmaxf(l2, l3));
    float e0 = __expf(l0 - m), e1 = __expf(l1 - m);
    float e2 = __expf(l2 - m), e3 = __expf(l3 - m);
    float inv = 1.0f / (e0 + e1 + e2 + e3);
    float aw[4] = { e0 * inv, e1 * inv, e2 * inv, e3 * inv };

    // this head's 8 pixel offsets (bf16)
    short8 ob = *reinterpret_cast<const short8*>(qpb + h * 8);
    float ofs[8];
    #pragma unroll
    for (int j = 0; j < 8; ++j) ofs[j] = bfu((unsigned short)ob[j]);

    const short* vb = v + (long)bsel * HWW * 128 + l * 8;

    float ac[8] = {0,0,0,0,0,0,0,0};
    #pragma unroll
    for (int p = 0; p < NPP; ++p) {
        float x = rx + ofs[p * 2 + 0];
        float y = ry + ofs[p * 2 + 1];
        float x0f = floorf(x), y0f = floorf(y);
        float wx = x - x0f, wy = y - y0f;
        int ix0 = (int)x0f, iy0 = (int)y0f;
        float wxs[2] = { 1.0f - wx, wx };
        float wys[2] = { 1.0f - wy, wy };
        #pragma unroll
        for (int cy = 0; cy < 2; ++cy) {
            int iy = iy0 + cy;
            bool vy = ((unsigned)iy < (unsigned)HH);
            int iyc = min(max(iy, 0), HH - 1);
            #pragma unroll
            for (int cx = 0; cx < 2; ++cx) {
                int ix = ix0 + cx;
                bool vx = ((unsigned)ix < (unsigned)WW);
                int ixc = min(max(ix, 0), WW - 1);
                float wgt = (vx && vy) ? (aw[p] * wxs[cx] * wys[cy]) : 0.0f;
                short8 g = *reinterpret_cast<const short8*>(vb + (iyc * WW + ixc) * 128);
                #pragma unroll
                for (int j = 0; j < 8; ++j)
                    ac[j] += wgt * bfu((unsigned short)g[j]);
            }
        }
    }
    short8 pk;
    #pragma unroll
    for (int j = 0; j < 8; ++j) pk[j] = f2bf(ac[j]);
    *reinterpret_cast<short8*>(agg + q * 128 + l * 8) = pk;
}

extern "C" void kernel_launch(void* const* d_in, const int* in_sizes, int n_in,
                              void* d_out, int out_size, void* d_ws, size_t ws_size,
                              hipStream_t stream) {
    const float* query = (const float*)d_in[0];
    const float* value = (const float*)d_in[1];
    const float* ref   = (const float*)d_in[2];
    const float* Wv    = (const float*)d_in[3];
    const float* bv    = (const float*)d_in[4];
    const float* Wo    = (const float*)d_in[5];
    const float* bo    = (const float*)d_in[6];
    const float* Wa    = (const float*)d_in[7];
    const float* ba    = (const float*)d_in[8];
    const float* Wout  = (const float*)d_in[9];
    const float* bout  = (const float*)d_in[10];
    float* out = (float*)d_out;

    // workspace layout (256B-aligned chunks)
    char* ws = (char*)d_ws;
    short* vbf   = (short*)ws;  ws += (long)BHW * 128 * 2;   // 7.37 MB
    short* wtv   = (short*)ws;  ws += 128 * 128 * 2;         // 32 KB
    short* wcat  = (short*)ws;  ws += 96 * 128 * 2;          // 24 KB
    short* woutt = (short*)ws;  ws += 128 * 128 * 2;         // 32 KB
    float* bcat  = (float*)ws;  ws += 128 * 4;               // 512 B
    short* qpb   = (short*)ws;  ws += (long)BQ * 96 * 2;     // 15.36 MB
    short* aggb  = (short*)ws;                               // 20.48 MB (bf16 [BQ,128])

    const int ntV = BHW / 128;   // 225
    const int ntQ = BQ / 128;    // 625
    const int gV = ntV < 512 ? ntV : 512;
    const int gQ = ntQ < 512 ? ntQ : 512;

    // 0) weight prep (bf16 transposed)
    prep_weights<<<64, 256, 0, stream>>>(Wv, Wo, Wa, Wout, bo, ba,
                                         wtv, wcat, woutt, bcat);
    // 1) value projection -> bf16 v
    gemm_pipe<128, true, true><<<gV, 256, 0, stream>>>(value, wtv, bv, vbf, ntV);
    // 2) fused offset+attn projection -> bf16 qp [BQ,96]
    gemm_pipe<96, true, true><<<gQ, 256, 0, stream>>>(query, wcat, bcat, qpb, ntQ);
    // 3) bilinear sampling + aggregation -> bf16 agg (no LDS, occupancy-first)
    deform_sample16<<<(BQ * 16) / 256, 256, 0, stream>>>(vbf, qpb, ref, aggb);
    // 4) output projection -> d_out
    gemm_pipe<128, false, false><<<gQ, 256, 0, stream>>>(aggb, woutt, bout, out, ntQ);
}